// Round 2
// baseline (207.486 us; speedup 1.0000x reference)
//
#include <hip/hip_runtime.h>
#include <hip/hip_bf16.h>

// Problem: out[b,j,k] = squash_j( s[b,j,k] ), s = sum_{i<2048,u<16} W[i,j,k,u] x[b,u,i]
// GEMM view: C[m=b(32), n=(j,k)(1024)] = A[m,(i,u)] B[(i,u),n], K=32768.
// W[i][j][k][u] strides (floats): i:16384, j:1024, k:16, u:1
// x[b][u][i]    strides (floats): b:32768, u:2048, i:1

#define B_SZ   32
#define IC     2048
#define NJ     16
#define NK     64
#define SOUT   (B_SZ*NJ*NK)      // 32768
#define KSTEPS 1024              // K-steps; each covers kdim=32 = (2 i's x 16 u)
#define KSPLIT 64                // K-splits across grid.y (was 32: 2 blk/CU -> 4 blk/CU)
#define SPW    (KSTEPS/KSPLIT)   // 16 steps per wave

typedef float v4f __attribute__((ext_vector_type(4)));
typedef short v8s __attribute__((ext_vector_type(8)));

// f32 -> bf16 round-to-nearest-even (bit trick)
static __device__ inline ushort f2bf(float f) {
    uint32_t u = __float_as_uint(f);
    u += 0x7FFFu + ((u >> 16) & 1u);
    return (ushort)(u >> 16);
}

// ---------------------------------------------------------------------------
// xprep: build A-fragments in bf16.
// kdim enumeration within a step: kk = q*8 + jj  ->  i_off = kk>>4, u = kk&15.
// A-operand layout (16x16x32 bf16): lane holds A[m = lane&15][kk = (lane>>4)*8 + jj].
// xb flat: [step(1024)][mt(2)][lane(64)][jj(8)] bf16; value =
//   bf16( x[b = mt*16 + (lane&15)][u = (q&1)*8 + jj][i = 2*step + (q>>1)] )
// ---------------------------------------------------------------------------
__global__ __launch_bounds__(256)
void caps_xprep(const float* __restrict__ x, ushort* __restrict__ xb) {
    int gid  = blockIdx.x * 256 + threadIdx.x;   // 131072 threads
    int lane = gid & 63;
    int mt   = (gid >> 6) & 1;
    int step = gid >> 7;
    int q    = lane >> 4;
    int b    = mt * 16 + (lane & 15);
    int i    = 2 * step + (q >> 1);
    int u0   = (q & 1) * 8;

    const float* xp = x + (size_t)b * (16 * IC) + (size_t)u0 * IC + i;
    ushort tmp[8];
    #pragma unroll
    for (int jj = 0; jj < 8; ++jj)
        tmp[jj] = f2bf(xp[(size_t)jj * IC]);
    *(v8s*)(xb + (size_t)gid * 8) = *(const v8s*)tmp;   // coalesced 16 B/lane store
}

// ---------------------------------------------------------------------------
// main: block = (j, split), 256 thr = 4 waves; wave wv = k'-tile (16 k's).
// Per K-step: load 2 KB W f32 (coalesced, read-once, nontemporal), cvt->bf16
// B-frag, 2 MFMA (two b-tiles). No LDS, no barriers.
// B-operand layout: lane holds B[kk = (lane>>4)*8 + jj][n = lane&15].
//   W addr: i = 2*step + (q>>1), u = (q&1)*8 + jj (8 consecutive floats).
// ---------------------------------------------------------------------------
__global__ __launch_bounds__(256, 4)
void caps_mfma(const ushort* __restrict__ xb, const float* __restrict__ W,
               float* __restrict__ part) {
    const int tid   = threadIdx.x;
    const int wv    = tid >> 6;       // k'-tile 0..3
    const int lane  = tid & 63;
    const int j     = blockIdx.x;     // 0..15
    const int split = blockIdx.y;     // 0..KSPLIT-1
    const int n     = lane & 15;
    const int q     = lane >> 4;
    const int step0 = split * SPW;

    v4f acc0 = {0.f, 0.f, 0.f, 0.f};
    v4f acc1 = {0.f, 0.f, 0.f, 0.f};

    const float*  wp = W + (size_t)(2 * step0 + (q >> 1)) * 16384
                         + (size_t)j * 1024 + (size_t)(wv * 16 + n) * 16 + (q & 1) * 8;
    const ushort* xp = xb + (size_t)step0 * 1024 + (size_t)lane * 8;

    #pragma unroll 4
    for (int s = 0; s < SPW; ++s) {
        v4f w0 = __builtin_nontemporal_load((const v4f*)wp);
        v4f w1 = __builtin_nontemporal_load(((const v4f*)wp) + 1);
        v8s a0 = *(const v8s*)(xp);          // b-tile 0 (b 0..15)
        v8s a1 = *(const v8s*)(xp + 512);    // b-tile 1 (b 16..31)
        v8s bb;
        bb[0] = (short)f2bf(w0.x); bb[1] = (short)f2bf(w0.y);
        bb[2] = (short)f2bf(w0.z); bb[3] = (short)f2bf(w0.w);
        bb[4] = (short)f2bf(w1.x); bb[5] = (short)f2bf(w1.y);
        bb[6] = (short)f2bf(w1.z); bb[7] = (short)f2bf(w1.w);
        acc0 = __builtin_amdgcn_mfma_f32_16x16x32_bf16(a0, bb, acc0, 0, 0, 0);
        acc1 = __builtin_amdgcn_mfma_f32_16x16x32_bf16(a1, bb, acc1, 0, 0, 0);
        wp += 2 * 16384;
        xp += 1024;
    }

    // C/D layout: col = lane&15 = n (k'), row = q*4 + reg = m (b).
    // part[split][b][j][k] : k = wv*16 + n
    float* pp = part + (size_t)split * SOUT + (size_t)j * NK + wv * 16 + n;
    #pragma unroll
    for (int r = 0; r < 4; ++r) {
        int m = q * 4 + r;
        pp[(size_t)m * 1024]        = acc0[r];
        pp[(size_t)(m + 16) * 1024] = acc1[r];
    }
}

// ---------------------------------------------------------------------------
// finish: sum K-splits, then squash over j (num_units axis, per torch source).
// 128 blocks = (b:32, k-chunk:4); 256 thr = (j:16, kc:16).
// ---------------------------------------------------------------------------
__global__ __launch_bounds__(256)
void caps_finish(const float* __restrict__ part, float* __restrict__ out) {
    __shared__ float ls[256];
    const int blk = blockIdx.x;
    const int b   = blk >> 2;
    const int k0  = (blk & 3) * 16;
    const int t   = threadIdx.x;
    const int jj  = t >> 4;
    const int kc  = t & 15;
    const size_t idx = (size_t)b * 1024 + (size_t)jj * NK + k0 + kc;

    float s = 0.0f;
    #pragma unroll 8
    for (int sp = 0; sp < KSPLIT; ++sp)
        s += part[(size_t)sp * SOUT + idx];
    ls[t] = s;
    __syncthreads();

    float msq = 0.0f;
    #pragma unroll
    for (int j2 = 0; j2 < NJ; ++j2) {
        float v = ls[j2 * 16 + kc];
        msq += v * v;
    }
    float mag = sqrtf(msq);
    out[idx] = s * (mag / (1.0f + msq));
}

extern "C" void kernel_launch(void* const* d_in, const int* in_sizes, int n_in,
                              void* d_out, int out_size, void* d_ws, size_t ws_size,
                              hipStream_t stream) {
    const float* x = (const float*)d_in[0];   // (32, 16, 2048) f32
    const float* W = (const float*)d_in[1];   // (1, 2048, 16, 64, 16) f32
    float* out  = (float*)d_out;              // (32, 16, 64) f32

    float*  part = (float*)d_ws;                            // 8 MB
    ushort* xb   = (ushort*)(part + (size_t)KSPLIT * SOUT); // 2 MB

    caps_xprep <<<512,               256, 0, stream>>>(x, xb);
    caps_mfma  <<<dim3(16, KSPLIT),  256, 0, stream>>>(xb, W, part);
    caps_finish<<<128,               256, 0, stream>>>(part, out);
}

// Round 3
// 205.417 us; speedup vs baseline: 1.0101x; 1.0101x over previous
//
#include <hip/hip_runtime.h>
#include <hip/hip_bf16.h>

// Problem: out[b,j,k] = squash_j( s[b,j,k] ), s = sum_{i<2048,u<16} W[i,j,k,u] x[b,u,i]
// GEMM view: C[m=b(32), n=(j,k)(1024)] = A[m,(i,u)] B[(i,u),n], K=32768.
// W[i][j][k][u] strides (floats): i:16384, j:1024, k:16, u:1
// x[b][u][i]    strides (floats): b:32768, u:2048, i:1

#define B_SZ   32
#define IC     2048
#define NJ     16
#define NK     64
#define SOUT   (B_SZ*NJ*NK)      // 32768
#define KSTEPS 1024              // K-steps; each covers kdim=32 = (2 i's x 16 u)
#define KSPLIT 64                // K-splits across grid.y
#define SPW    (KSTEPS/KSPLIT)   // 16 steps per block
#define JPB    2                 // j's per block (grid.x = NJ/JPB = 8)

typedef float v4f __attribute__((ext_vector_type(4)));
typedef short v8s __attribute__((ext_vector_type(8)));

// f32 -> bf16 round-to-nearest-even (bit trick)
static __device__ inline ushort f2bf(float f) {
    uint32_t u = __float_as_uint(f);
    u += 0x7FFFu + ((u >> 16) & 1u);
    return (ushort)(u >> 16);
}

// ---------------------------------------------------------------------------
// xprep: build A-fragments in bf16.
// kdim enumeration within a step: kk = q*8 + jj  ->  i_off = kk>>4, u = kk&15.
// A-operand layout (16x16x32 bf16): lane holds A[m = lane&15][kk = (lane>>4)*8 + jj].
// xb flat: [step(1024)][mt(2)][lane(64)][jj(8)] bf16; value =
//   bf16( x[b = mt*16 + (lane&15)][u = (q&1)*8 + jj][i = 2*step + (q>>1)] )
// ---------------------------------------------------------------------------
__global__ __launch_bounds__(256)
void caps_xprep(const float* __restrict__ x, ushort* __restrict__ xb) {
    int gid  = blockIdx.x * 256 + threadIdx.x;   // 131072 threads
    int lane = gid & 63;
    int mt   = (gid >> 6) & 1;
    int step = gid >> 7;
    int q    = lane >> 4;
    int b    = mt * 16 + (lane & 15);
    int i    = 2 * step + (q >> 1);
    int u0   = (q & 1) * 8;

    const float* xp = x + (size_t)b * (16 * IC) + (size_t)u0 * IC + i;
    ushort tmp[8];
    #pragma unroll
    for (int jj = 0; jj < 8; ++jj)
        tmp[jj] = f2bf(xp[(size_t)jj * IC]);
    *(v8s*)(xb + (size_t)gid * 8) = *(const v8s*)tmp;   // coalesced 16 B/lane store
}

// ---------------------------------------------------------------------------
// main: block = (jp, split), 256 thr = 4 waves; wave wv = k'-tile (16 k's).
// Each block covers TWO j's (j0 = 2*jp, j0+1): per K-step a wave issues 4 W
// dwordx4 loads (2 KB in flight), converts 2 B-frags, does 4 MFMA — double the
// in-flight memory and half the loop overhead of the 1-j version. A-frags
// (xb) are loaded once per step and reused across both j's. No LDS/barriers.
// B-operand layout: lane holds B[kk = (lane>>4)*8 + jj][n = lane&15].
//   W addr: i = 2*step + (q>>1), u = (q&1)*8 + jj (8 consecutive floats).
// ---------------------------------------------------------------------------
__global__ __launch_bounds__(256)
void caps_mfma(const ushort* __restrict__ xb, const float* __restrict__ W,
               float* __restrict__ part) {
    const int tid   = threadIdx.x;
    const int wv    = tid >> 6;       // k'-tile 0..3
    const int lane  = tid & 63;
    const int j0    = blockIdx.x * JPB;  // 0,2,..,14
    const int split = blockIdx.y;     // 0..KSPLIT-1
    const int n     = lane & 15;
    const int q     = lane >> 4;
    const int step0 = split * SPW;

    v4f acc00 = {0.f, 0.f, 0.f, 0.f};   // j0, b 0..15
    v4f acc01 = {0.f, 0.f, 0.f, 0.f};   // j0, b 16..31
    v4f acc10 = {0.f, 0.f, 0.f, 0.f};   // j1, b 0..15
    v4f acc11 = {0.f, 0.f, 0.f, 0.f};   // j1, b 16..31

    const float*  wp = W + (size_t)(2 * step0 + (q >> 1)) * 16384
                         + (size_t)j0 * 1024 + (size_t)(wv * 16 + n) * 16 + (q & 1) * 8;
    const ushort* xp = xb + (size_t)step0 * 1024 + (size_t)lane * 8;

    #pragma unroll 2
    for (int s = 0; s < SPW; ++s) {
        v4f w00 = *(const v4f*)(wp);
        v4f w01 = *(const v4f*)(wp + 4);
        v4f w10 = *(const v4f*)(wp + 1024);
        v4f w11 = *(const v4f*)(wp + 1028);
        v8s a0 = *(const v8s*)(xp);          // b-tile 0 (b 0..15)
        v8s a1 = *(const v8s*)(xp + 512);    // b-tile 1 (b 16..31)
        v8s b0, b1;
        b0[0] = (short)f2bf(w00.x); b0[1] = (short)f2bf(w00.y);
        b0[2] = (short)f2bf(w00.z); b0[3] = (short)f2bf(w00.w);
        b0[4] = (short)f2bf(w01.x); b0[5] = (short)f2bf(w01.y);
        b0[6] = (short)f2bf(w01.z); b0[7] = (short)f2bf(w01.w);
        b1[0] = (short)f2bf(w10.x); b1[1] = (short)f2bf(w10.y);
        b1[2] = (short)f2bf(w10.z); b1[3] = (short)f2bf(w10.w);
        b1[4] = (short)f2bf(w11.x); b1[5] = (short)f2bf(w11.y);
        b1[6] = (short)f2bf(w11.z); b1[7] = (short)f2bf(w11.w);
        acc00 = __builtin_amdgcn_mfma_f32_16x16x32_bf16(a0, b0, acc00, 0, 0, 0);
        acc01 = __builtin_amdgcn_mfma_f32_16x16x32_bf16(a1, b0, acc01, 0, 0, 0);
        acc10 = __builtin_amdgcn_mfma_f32_16x16x32_bf16(a0, b1, acc10, 0, 0, 0);
        acc11 = __builtin_amdgcn_mfma_f32_16x16x32_bf16(a1, b1, acc11, 0, 0, 0);
        wp += 2 * 16384;
        xp += 1024;
    }

    // C/D layout: col = lane&15 = n (k'), row = q*4 + reg = m (b).
    // part[split][b][j][k] : k = wv*16 + n ; j1 is +NK floats from j0.
    float* pp = part + (size_t)split * SOUT + (size_t)j0 * NK + wv * 16 + n;
    #pragma unroll
    for (int r = 0; r < 4; ++r) {
        int m = q * 4 + r;
        pp[(size_t)m * 1024]             = acc00[r];
        pp[(size_t)(m + 16) * 1024]      = acc01[r];
        pp[(size_t)m * 1024 + NK]        = acc10[r];
        pp[(size_t)(m + 16) * 1024 + NK] = acc11[r];
    }
}

// ---------------------------------------------------------------------------
// finish: sum K-splits, then squash over j (num_units axis, per torch source).
// 128 blocks = (b:32, k-chunk:4); 256 thr = (j:16, kc:16).
// ---------------------------------------------------------------------------
__global__ __launch_bounds__(256)
void caps_finish(const float* __restrict__ part, float* __restrict__ out) {
    __shared__ float ls[256];
    const int blk = blockIdx.x;
    const int b   = blk >> 2;
    const int k0  = (blk & 3) * 16;
    const int t   = threadIdx.x;
    const int jj  = t >> 4;
    const int kc  = t & 15;
    const size_t idx = (size_t)b * 1024 + (size_t)jj * NK + k0 + kc;

    float s = 0.0f;
    #pragma unroll 8
    for (int sp = 0; sp < KSPLIT; ++sp)
        s += part[(size_t)sp * SOUT + idx];
    ls[t] = s;
    __syncthreads();

    float msq = 0.0f;
    #pragma unroll
    for (int j2 = 0; j2 < NJ; ++j2) {
        float v = ls[j2 * 16 + kc];
        msq += v * v;
    }
    float mag = sqrtf(msq);
    out[idx] = s * (mag / (1.0f + msq));
}

extern "C" void kernel_launch(void* const* d_in, const int* in_sizes, int n_in,
                              void* d_out, int out_size, void* d_ws, size_t ws_size,
                              hipStream_t stream) {
    const float* x = (const float*)d_in[0];   // (32, 16, 2048) f32
    const float* W = (const float*)d_in[1];   // (1, 2048, 16, 64, 16) f32
    float* out  = (float*)d_out;              // (32, 16, 64) f32

    float*  part = (float*)d_ws;                            // 8 MB
    ushort* xb   = (ushort*)(part + (size_t)KSPLIT * SOUT); // 2 MB

    caps_xprep <<<512,                  256, 0, stream>>>(x, xb);
    caps_mfma  <<<dim3(NJ/JPB, KSPLIT), 256, 0, stream>>>(xb, W, part);
    caps_finish<<<128,                  256, 0, stream>>>(part, out);
}